// Round 3
// baseline (2121.778 us; speedup 1.0000x reference)
//
#include <hip/hip_runtime.h>
#include <cstdint>

#define SLEN 1024
#define BATCH 64
#define EDIM 256
#define HDIM 128   // hidden per direction
#define GDIM 512   // 4*HDIM
#define NTAG 4

// ---------------------------------------------------------------------------
// ws layout (floats), chunked to fit ws_size:
//   Z  : [L][B][1024]  gate-preactivation chunk (cols 0..511 fwd, 512..1023 rev)
//   H  : [S][B][256]   (cols 0..127 fwd h, 128..255 rev h)      16777216
//   F  : [S][B][4]     emissions                                   262144
//   ST : [2][B][256]   LSTM carry (h | c) per (dir,b)               32768
// L = largest pow2 divisor of 1024 s.t. everything fits in ws_size.
// ---------------------------------------------------------------------------

__device__ __forceinline__ float sigm(float x) {
    return 1.0f / (1.0f + expf(-x));
}

// ---------------------------------------------------------------------------
// Kernel 1: fused embedding-gather + input-projection GEMM for one S-chunk.
// Z[r_loc][dir*512+c] = embed[sent[b][s_glob]] . w_ih_dir[c] + b_ih[c] + b_hh[c]
// r_loc = s_loc*64 + b;  s_glob = (dir ? base_r : base_f) + s_loc.
// Tiles: 128 rows x 128 cols, kc=64, 256 threads, 8x8 micro.
// ---------------------------------------------------------------------------
__global__ __launch_bounds__(256) void gemm_zin(
    const int* __restrict__ sent, const float* __restrict__ embed,
    const float* __restrict__ w_ih_f, const float* __restrict__ w_ih_r,
    const float* __restrict__ b_ih_f, const float* __restrict__ b_hh_f,
    const float* __restrict__ b_ih_r, const float* __restrict__ b_hh_r,
    float* __restrict__ Z, int base_f, int base_r)
{
    __shared__ __align__(16) float As[64 * 128];
    __shared__ __align__(16) float Bs[64 * 128];

    const int t   = threadIdx.x;
    const int mt  = blockIdx.x;        // M tile within chunk
    const int nt  = blockIdx.y;        // 0..7 (N tile; 0-3 fwd, 4-7 rev)
    const int dir = nt >> 2;
    const float* W  = dir ? w_ih_r : w_ih_f;
    const float* bi = dir ? b_ih_r : b_ih_f;
    const float* bh = dir ? b_hh_r : b_hh_f;
    const int ncol = (nt & 3) * 128;   // col base within direction
    const int r0   = mt * 128;         // row base within chunk

    // staging: 2 threads per row, each stages a 32-float half of the k=256 row
    const int srow = t >> 1;
    const int half = t & 1;
    const int r_loc = r0 + srow;
    const int s_loc = r_loc >> 6;
    const int b_    = r_loc & 63;
    const int s_glob = (dir ? base_r : base_f) + s_loc;
    const int tok = sent[b_ * SLEN + s_glob];
    const float* arow = embed + (size_t)tok * EDIM + half * 32;
    const float* brow = W + (size_t)(ncol + srow) * EDIM + half * 32;

    const int tx = t & 15, ty = t >> 4;

    float2 acc[8][4];
    #pragma unroll
    for (int i = 0; i < 8; ++i)
        #pragma unroll
        for (int jj = 0; jj < 4; ++jj) { acc[i][jj].x = 0.f; acc[i][jj].y = 0.f; }

    for (int kt = 0; kt < 4; ++kt) {
        const int k0 = kt * 64;
        __syncthreads();
        #pragma unroll
        for (int i = 0; i < 8; ++i) {
            float4 v = *(const float4*)(arow + k0 + i * 4);
            int kk = half * 32 + i * 4;
            As[(kk + 0) * 128 + srow] = v.x;
            As[(kk + 1) * 128 + srow] = v.y;
            As[(kk + 2) * 128 + srow] = v.z;
            As[(kk + 3) * 128 + srow] = v.w;
        }
        #pragma unroll
        for (int i = 0; i < 8; ++i) {
            float4 v = *(const float4*)(brow + k0 + i * 4);
            int kk = half * 32 + i * 4;
            Bs[(kk + 0) * 128 + srow] = v.x;
            Bs[(kk + 1) * 128 + srow] = v.y;
            Bs[(kk + 2) * 128 + srow] = v.z;
            Bs[(kk + 3) * 128 + srow] = v.w;
        }
        __syncthreads();

        #pragma unroll 8
        for (int k = 0; k < 64; ++k) {
            const float4 a0 = *(const float4*)&As[k * 128 + ty * 8];
            const float4 a1 = *(const float4*)&As[k * 128 + ty * 8 + 4];
            const float4 bq0 = *(const float4*)&Bs[k * 128 + tx * 8];
            const float4 bq1 = *(const float4*)&Bs[k * 128 + tx * 8 + 4];
            float av[8] = {a0.x, a0.y, a0.z, a0.w, a1.x, a1.y, a1.z, a1.w};
            float2 bv[4] = {{bq0.x, bq0.y}, {bq0.z, bq0.w},
                            {bq1.x, bq1.y}, {bq1.z, bq1.w}};
            #pragma unroll
            for (int i = 0; i < 8; ++i) {
                #pragma unroll
                for (int jj = 0; jj < 4; ++jj) {
                    acc[i][jj].x = fmaf(av[i], bv[jj].x, acc[i][jj].x);
                    acc[i][jj].y = fmaf(av[i], bv[jj].y, acc[i][jj].y);
                }
            }
        }
    }

    float bias[8];
    #pragma unroll
    for (int jj = 0; jj < 8; ++jj)
        bias[jj] = bi[ncol + tx * 8 + jj] + bh[ncol + tx * 8 + jj];

    #pragma unroll
    for (int i = 0; i < 8; ++i) {
        int rr = r0 + ty * 8 + i;
        float* zp = Z + (size_t)rr * 1024 + dir * 512 + ncol + tx * 8;
        float4 o0, o1;
        o0.x = acc[i][0].x + bias[0]; o0.y = acc[i][0].y + bias[1];
        o0.z = acc[i][1].x + bias[2]; o0.w = acc[i][1].y + bias[3];
        o1.x = acc[i][2].x + bias[4]; o1.y = acc[i][2].y + bias[5];
        o1.z = acc[i][3].x + bias[6]; o1.w = acc[i][3].y + bias[7];
        *(float4*)zp       = o0;
        *(float4*)(zp + 4) = o1;
    }
}

// ---------------------------------------------------------------------------
// Kernel 2: LSTM recurrence over one S-chunk of L steps, carrying (h,c) in ST.
// One block per (batch, direction): 128 blocks, 512 threads.
// Thread j owns gate-row j: w_hh[j][0:128] in VGPRs; h broadcast via LDS.
// ---------------------------------------------------------------------------
__global__ __launch_bounds__(512) void lstm_rec(
    const float* __restrict__ Z, const float* __restrict__ w_hh_f,
    const float* __restrict__ w_hh_r, float* __restrict__ H,
    float* __restrict__ ST, int base_f, int base_r, int L, int first)
{
    const int bid = blockIdx.x;
    const int b   = bid & 63;
    const int dir = bid >> 6;
    const int j   = threadIdx.x;

    const float* Wr = (dir ? w_hh_r : w_hh_f) + (size_t)j * HDIM;
    float2 w[64];
    #pragma unroll
    for (int k4 = 0; k4 < 32; ++k4) {
        float4 wv = ((const float4*)Wr)[k4];
        w[2 * k4].x     = wv.x; w[2 * k4].y     = wv.y;
        w[2 * k4 + 1].x = wv.z; w[2 * k4 + 1].y = wv.w;
    }

    __shared__ __align__(16) float sh_h[HDIM];
    __shared__ float sh_z[GDIM];
    float* stp = ST + (size_t)(dir * 64 + b) * 256;
    float c = 0.0f;
    if (j < HDIM) {
        if (first) { sh_h[j] = 0.0f; }
        else       { sh_h[j] = stp[j]; c = stp[HDIM + j]; }
    }
    __syncthreads();

    // z stream: per step, element at Z[(s_loc*64 + b)*1024 + dir*512 + j]
    const float* Zb = Z + (size_t)b * 1024 + dir * 512 + j;
    // iteration t -> s_loc: fwd t, rev L-1-t
    float z0 = Zb[(size_t)(dir ? (L - 1) : 0) * 65536];
    float z1 = Zb[(size_t)(dir ? (L - 2) : 1) * 65536];

    for (int t = 0; t < L; ++t) {
        float z2 = 0.0f;
        if (t + 2 < L) {
            int s2 = dir ? (L - 3 - t) : (t + 2);
            z2 = Zb[(size_t)s2 * 65536];
        }
        // matvec: z += w_hh[j] . h   (full 128-wide dot: 32 float4 of h)
        float2 acc[4] = {{0, 0}, {0, 0}, {0, 0}, {0, 0}};
        const float4* h4p = (const float4*)sh_h;
        #pragma unroll
        for (int k4 = 0; k4 < 32; ++k4) {
            float4 h4 = h4p[k4];
            float2 w0 = w[2 * k4], w1 = w[2 * k4 + 1];
            int ia = k4 & 3, ib = (k4 + 2) & 3;
            acc[ia].x = fmaf(w0.x, h4.x, acc[ia].x);
            acc[ia].y = fmaf(w0.y, h4.y, acc[ia].y);
            acc[ib].x = fmaf(w1.x, h4.z, acc[ib].x);
            acc[ib].y = fmaf(w1.y, h4.w, acc[ib].y);
        }
        float zacc = z0 + ((acc[0].x + acc[0].y) + (acc[1].x + acc[1].y))
                        + ((acc[2].x + acc[2].y) + (acc[3].x + acc[3].y));
        sh_z[j] = zacc;
        __syncthreads();
        if (j < HDIM) {
            float iv = sh_z[j], fv = sh_z[j + 128];
            float gv = sh_z[j + 256], ov = sh_z[j + 384];
            c = sigm(fv) * c + sigm(iv) * tanhf(gv);
            float hv = sigm(ov) * tanhf(c);
            sh_h[j] = hv;
            int s_glob = dir ? (base_r + (L - 1 - t)) : (base_f + t);
            H[((size_t)s_glob * 64 + b) * 256 + dir * 128 + j] = hv;
        }
        __syncthreads();
        z0 = z1; z1 = z2;
    }

    // persist carry for next chunk
    if (j < HDIM) {
        stp[j] = sh_h[j];
        stp[HDIM + j] = c;
    }
}

// ---------------------------------------------------------------------------
// Kernel 3: emissions  F[r][t] = H[r] . w_out[t] + b_out[t]
// ---------------------------------------------------------------------------
__global__ __launch_bounds__(256) void emissions_k(
    const float* __restrict__ H, const float* __restrict__ w_out,
    const float* __restrict__ b_out, float* __restrict__ F)
{
    const int gid = blockIdx.x * 256 + threadIdx.x;
    const int r   = gid >> 2;
    const int tg  = gid & 3;
    const float4* h4 = (const float4*)(H + (size_t)r * 256);
    const float4* w4 = (const float4*)(w_out + (size_t)tg * 256);
    float a0 = 0.f, a1 = 0.f, a2 = 0.f, a3 = 0.f;
    #pragma unroll 8
    for (int k = 0; k < 64; ++k) {
        float4 h = h4[k], w = w4[k];
        a0 = fmaf(h.x, w.x, a0); a1 = fmaf(h.y, w.y, a1);
        a2 = fmaf(h.z, w.z, a2); a3 = fmaf(h.w, w.w, a3);
    }
    F[gid] = ((a0 + a1) + (a2 + a3)) + b_out[tg];
}

// ---------------------------------------------------------------------------
// Kernel 4: Viterbi. One block (1 wave) per batch.
// ---------------------------------------------------------------------------
__device__ __forceinline__ unsigned compose_map(unsigned a, unsigned b) {
    // (a o b)(t) = a[b[t]]; byte j of result = a_byte[b_byte[j]]
    unsigned r = 0;
    #pragma unroll
    for (int jj = 0; jj < 4; ++jj) {
        unsigned bj = (b >> (jj * 8)) & 3u;
        unsigned aj = (a >> (bj * 8)) & 3u;
        r |= aj << (jj * 8);
    }
    return r;
}

__global__ __launch_bounds__(64) void viterbi_k(
    const float* __restrict__ F, const float* __restrict__ start_t,
    const float* __restrict__ end_t, const float* __restrict__ trans,
    int* __restrict__ out)
{
    const int b    = blockIdx.x;
    const int lane = threadIdx.x;
    __shared__ __align__(16) float sfeat[SLEN][NTAG];
    __shared__ unsigned sbp[SLEN];

    #pragma unroll
    for (int i = 0; i < 16; ++i) {
        int s = i * 64 + lane;
        ((float4*)sfeat)[s] = *(const float4*)(F + ((size_t)s * BATCH + b) * NTAG);
    }
    __syncthreads();

    const int cur = lane & 3;
    float tr0 = trans[0 * 4 + cur], tr1 = trans[1 * 4 + cur];
    float tr2 = trans[2 * 4 + cur], tr3 = trans[3 * 4 + cur];
    float sc = start_t[cur] + sfeat[0][cur];

    for (int s = 1; s < SLEN; ++s) {
        float ft = sfeat[s][cur];
        float s0 = __shfl(sc, 0), s1 = __shfl(sc, 1);
        float s2 = __shfl(sc, 2), s3 = __shfl(sc, 3);
        float c0 = s0 + tr0, c1 = s1 + tr1, c2 = s2 + tr2, c3 = s3 + tr3;
        float best = c0; int arg = 0;
        if (c1 > best) { best = c1; arg = 1; }
        if (c2 > best) { best = c2; arg = 2; }
        if (c3 > best) { best = c3; arg = 3; }
        sc = best + ft;
        unsigned bp = (unsigned)arg;
        unsigned b0 = __shfl(bp, 0), b1 = __shfl(bp, 1);
        unsigned b2 = __shfl(bp, 2), b3 = __shfl(bp, 3);
        if (lane == 0) sbp[s] = b0 | (b1 << 8) | (b2 << 16) | (b3 << 24);
    }
    sc += end_t[cur];
    float f0 = __shfl(sc, 0), f1 = __shfl(sc, 1);
    float f2 = __shfl(sc, 2), f3 = __shfl(sc, 3);
    int last = 0; float bb = f0;
    if (f1 > bb) { bb = f1; last = 1; }
    if (f2 > bb) { bb = f2; last = 2; }
    if (f3 > bb) { bb = f3; last = 3; }
    __syncthreads();

    // segment of 16 maps per lane; m[k] maps tag at s -> tag at s-1
    unsigned m[16];
    #pragma unroll
    for (int k = 0; k < 16; ++k) {
        int s = lane * 16 + k;
        m[k] = (s >= 1) ? sbp[s] : 0x03020100u;
    }
    unsigned G = m[15];
    #pragma unroll
    for (int k = 14; k >= 0; --k) G = compose_map(m[k], G);
    unsigned R = G;
    #pragma unroll
    for (int d = 1; d < 64; d <<= 1) {
        unsigned o = __shfl_down(R, d);
        if (lane + d < 64) R = compose_map(R, o);
    }
    unsigned P = __shfl_down(R, 1);   // P_i = R_{i+1}; P_63 = identity
    if (lane == 63) P = 0x03020100u;

    int tcur = (int)((P >> (last * 8)) & 3u);  // tag at s = 16*lane + 15
    int* ob = out + b * SLEN + lane * 16;
    ob[15] = tcur;
    #pragma unroll
    for (int k = 15; k >= 1; --k) {
        tcur = (int)((m[k] >> (tcur * 8)) & 3u);
        ob[k - 1] = tcur;
    }
}

// ---------------------------------------------------------------------------
extern "C" void kernel_launch(void* const* d_in, const int* in_sizes, int n_in,
                              void* d_out, int out_size, void* d_ws, size_t ws_size,
                              hipStream_t stream)
{
    const int*   sent    = (const int*)d_in[0];
    const float* embed   = (const float*)d_in[1];
    const float* w_ih_f  = (const float*)d_in[2];
    const float* w_hh_f  = (const float*)d_in[3];
    const float* b_ih_f  = (const float*)d_in[4];
    const float* b_hh_f  = (const float*)d_in[5];
    const float* w_ih_r  = (const float*)d_in[6];
    const float* w_hh_r  = (const float*)d_in[7];
    const float* b_ih_r  = (const float*)d_in[8];
    const float* b_hh_r  = (const float*)d_in[9];
    const float* w_out   = (const float*)d_in[10];
    const float* b_out   = (const float*)d_in[11];
    const float* start_t = (const float*)d_in[12];
    const float* end_t   = (const float*)d_in[13];
    const float* trans   = (const float*)d_in[14];
    int* out = (int*)d_out;

    // fixed-footprint floats: H + F + ST
    const size_t H_FLOATS  = (size_t)SLEN * BATCH * 256;   // 16777216
    const size_t F_FLOATS  = (size_t)SLEN * BATCH * NTAG;  //   262144
    const size_t ST_FLOATS = (size_t)2 * BATCH * 256;      //    32768
    const size_t FIXED = H_FLOATS + F_FLOATS + ST_FLOATS;

    // pick chunk length L (pow2 divisor of SLEN) so Z chunk + fixed fits ws
    int L = SLEN;
    while (L > 32) {
        size_t need = ((size_t)L * BATCH * 1024 + FIXED) * sizeof(float);
        if (need <= ws_size) break;
        L >>= 1;
    }

    float* Z  = (float*)d_ws;                       // L*65536 floats
    float* H  = Z + (size_t)L * BATCH * 1024;
    float* F  = H + H_FLOATS;
    float* ST = F + F_FLOATS;

    const int nch = SLEN / L;
    for (int c = 0; c < nch; ++c) {
        const int base_f = c * L;
        const int base_r = SLEN - (c + 1) * L;
        gemm_zin<<<dim3(L / 2, 8), 256, 0, stream>>>(
            sent, embed, w_ih_f, w_ih_r, b_ih_f, b_hh_f, b_ih_r, b_hh_r,
            Z, base_f, base_r);
        lstm_rec<<<128, 512, 0, stream>>>(
            Z, w_hh_f, w_hh_r, H, ST, base_f, base_r, L, c == 0 ? 1 : 0);
    }
    emissions_k<<<1024, 256, 0, stream>>>(H, w_out, b_out, F);
    viterbi_k<<<64, 64, 0, stream>>>(F, start_t, end_t, trans, out);
}

// Round 4
// 1815.069 us; speedup vs baseline: 1.1690x; 1.1690x over previous
//
#include <hip/hip_runtime.h>
#include <cstdint>

#define SLEN 1024
#define BATCH 64
#define EDIM 256
#define HDIM 128   // hidden per direction
#define GDIM 512   // 4*HDIM
#define NTAG 4

// ---------------------------------------------------------------------------
// ws layout (floats), chunked to fit ws_size:
//   Z  : [L][B][1024]  gate-preactivation chunk (cols 0..511 fwd, 512..1023 rev)
//   H  : [S][B][256]   (cols 0..127 fwd h, 128..255 rev h)      16777216
//   F  : [S][B][4]     emissions                                   262144
//   ST : [2][B][256]   LSTM carry (h | c) per (dir,b)               32768
// ---------------------------------------------------------------------------

__device__ __forceinline__ float sigm(float x) {
    return 1.0f / (1.0f + expf(-x));
}

// ---------------------------------------------------------------------------
// Kernel 1: fused embedding-gather + input-projection GEMM for one S-chunk.
// (unchanged from round 3 — optimize next round if it tops the profile)
// ---------------------------------------------------------------------------
__global__ __launch_bounds__(256) void gemm_zin(
    const int* __restrict__ sent, const float* __restrict__ embed,
    const float* __restrict__ w_ih_f, const float* __restrict__ w_ih_r,
    const float* __restrict__ b_ih_f, const float* __restrict__ b_hh_f,
    const float* __restrict__ b_ih_r, const float* __restrict__ b_hh_r,
    float* __restrict__ Z, int base_f, int base_r)
{
    __shared__ __align__(16) float As[64 * 128];
    __shared__ __align__(16) float Bs[64 * 128];

    const int t   = threadIdx.x;
    const int mt  = blockIdx.x;
    const int nt  = blockIdx.y;
    const int dir = nt >> 2;
    const float* W  = dir ? w_ih_r : w_ih_f;
    const float* bi = dir ? b_ih_r : b_ih_f;
    const float* bh = dir ? b_hh_r : b_hh_f;
    const int ncol = (nt & 3) * 128;
    const int r0   = mt * 128;

    const int srow = t >> 1;
    const int half = t & 1;
    const int r_loc = r0 + srow;
    const int s_loc = r_loc >> 6;
    const int b_    = r_loc & 63;
    const int s_glob = (dir ? base_r : base_f) + s_loc;
    const int tok = sent[b_ * SLEN + s_glob];
    const float* arow = embed + (size_t)tok * EDIM + half * 32;
    const float* brow = W + (size_t)(ncol + srow) * EDIM + half * 32;

    const int tx = t & 15, ty = t >> 4;

    float2 acc[8][4];
    #pragma unroll
    for (int i = 0; i < 8; ++i)
        #pragma unroll
        for (int jj = 0; jj < 4; ++jj) { acc[i][jj].x = 0.f; acc[i][jj].y = 0.f; }

    for (int kt = 0; kt < 4; ++kt) {
        const int k0 = kt * 64;
        __syncthreads();
        #pragma unroll
        for (int i = 0; i < 8; ++i) {
            float4 v = *(const float4*)(arow + k0 + i * 4);
            int kk = half * 32 + i * 4;
            As[(kk + 0) * 128 + srow] = v.x;
            As[(kk + 1) * 128 + srow] = v.y;
            As[(kk + 2) * 128 + srow] = v.z;
            As[(kk + 3) * 128 + srow] = v.w;
        }
        #pragma unroll
        for (int i = 0; i < 8; ++i) {
            float4 v = *(const float4*)(brow + k0 + i * 4);
            int kk = half * 32 + i * 4;
            Bs[(kk + 0) * 128 + srow] = v.x;
            Bs[(kk + 1) * 128 + srow] = v.y;
            Bs[(kk + 2) * 128 + srow] = v.z;
            Bs[(kk + 3) * 128 + srow] = v.w;
        }
        __syncthreads();

        #pragma unroll 8
        for (int k = 0; k < 64; ++k) {
            const float4 a0 = *(const float4*)&As[k * 128 + ty * 8];
            const float4 a1 = *(const float4*)&As[k * 128 + ty * 8 + 4];
            const float4 bq0 = *(const float4*)&Bs[k * 128 + tx * 8];
            const float4 bq1 = *(const float4*)&Bs[k * 128 + tx * 8 + 4];
            float av[8] = {a0.x, a0.y, a0.z, a0.w, a1.x, a1.y, a1.z, a1.w};
            float2 bv[4] = {{bq0.x, bq0.y}, {bq0.z, bq0.w},
                            {bq1.x, bq1.y}, {bq1.z, bq1.w}};
            #pragma unroll
            for (int i = 0; i < 8; ++i) {
                #pragma unroll
                for (int jj = 0; jj < 4; ++jj) {
                    acc[i][jj].x = fmaf(av[i], bv[jj].x, acc[i][jj].x);
                    acc[i][jj].y = fmaf(av[i], bv[jj].y, acc[i][jj].y);
                }
            }
        }
    }

    float bias[8];
    #pragma unroll
    for (int jj = 0; jj < 8; ++jj)
        bias[jj] = bi[ncol + tx * 8 + jj] + bh[ncol + tx * 8 + jj];

    #pragma unroll
    for (int i = 0; i < 8; ++i) {
        int rr = r0 + ty * 8 + i;
        float* zp = Z + (size_t)rr * 1024 + dir * 512 + ncol + tx * 8;
        float4 o0, o1;
        o0.x = acc[i][0].x + bias[0]; o0.y = acc[i][0].y + bias[1];
        o0.z = acc[i][1].x + bias[2]; o0.w = acc[i][1].y + bias[3];
        o1.x = acc[i][2].x + bias[4]; o1.y = acc[i][2].y + bias[5];
        o1.z = acc[i][3].x + bias[6]; o1.w = acc[i][3].y + bias[7];
        *(float4*)zp       = o0;
        *(float4*)(zp + 4) = o1;
    }
}

// ---------------------------------------------------------------------------
// Kernel 2 (REWRITTEN): LSTM recurrence, LDS-traffic-minimized.
// 128 blocks (one per batch x dir), 256 threads (4 waves).
// Thread q: kq = q&3 (k-slice [kq*32, kq*32+32)), un = q>>2 (units un, un+64).
// Computes 8 partial dots (2 units x 4 gates x 32 k) with w_hh slice (256
// floats) in VGPRs. Partials exchanged via padded LDS; gate phase on q<128
// with c in-register. Z prefetched one step ahead (covers HBM latency).
// LDS/step: 32 b128 h-reads + ~16 exchange insts (vs 256 b128 before).
// ---------------------------------------------------------------------------
__global__ __launch_bounds__(256, 1) void lstm_rec(
    const float* __restrict__ Z, const float* __restrict__ w_hh_f,
    const float* __restrict__ w_hh_r, float* __restrict__ H,
    float* __restrict__ ST, int base_f, int base_r, int L, int first)
{
    const int bid = blockIdx.x;
    const int b   = bid & 63;
    const int dir = bid >> 6;
    const int q   = threadIdx.x;
    const int kq  = q & 3;
    const int un  = q >> 2;          // 0..63

    const float* Whh = dir ? w_hh_r : w_hh_f;

    // register-resident w_hh slice: [unit 0/1][gate][8 x float4]
    float4 w4[2][4][8];
    #pragma unroll
    for (int u = 0; u < 2; ++u) {
        const int j = un + u * 64;
        #pragma unroll
        for (int g = 0; g < 4; ++g) {
            const float4* src =
                (const float4*)(Whh + ((size_t)(g * 128 + j) * 128 + kq * 32));
            #pragma unroll
            for (int i = 0; i < 8; ++i) w4[u][g][i] = src[i];
        }
    }

    // sh_h: h[k] at (k>>5)*40 + (k&31)  -> kq groups hit disjoint bank sets
    __shared__ __align__(16) float sh_h[4 * 40];
    // sh_part: partial(j, kq, g) at j*20 + kq*4 + g  (20-stride spreads banks)
    __shared__ __align__(16) float sh_part[128 * 20];

    float* stp = ST + (size_t)(dir * 64 + b) * 256;
    float c = 0.0f;
    if (q < 128) {
        float h0 = first ? 0.0f : stp[q];
        c        = first ? 0.0f : stp[128 + q];
        sh_h[(q >> 5) * 40 + (q & 31)] = h0;
    }
    __syncthreads();

    // Z access for gate threads (q<128 => unit j=q; gate g at +g*128)
    const float* Zb = Z + (size_t)b * 1024 + dir * 512 + q;
    float za0 = 0.f, za1 = 0.f, za2 = 0.f, za3 = 0.f;
    if (q < 128) {
        const int s0 = dir ? (L - 1) : 0;
        const float* p = Zb + (size_t)s0 * 65536;
        za0 = p[0]; za1 = p[128]; za2 = p[256]; za3 = p[384];
    }

    for (int t = 0; t < L; ++t) {
        // prefetch z for step t+1 (full-step latency cover)
        float zb0 = 0.f, zb1 = 0.f, zb2 = 0.f, zb3 = 0.f;
        if (q < 128) {
            const int t1 = (t + 1 < L) ? (t + 1) : t;
            const int s1 = dir ? (L - 1 - t1) : t1;
            const float* p = Zb + (size_t)s1 * 65536;
            zb0 = p[0]; zb1 = p[128]; zb2 = p[256]; zb3 = p[384];
        }

        // matvec partials over this thread's 32-k slice
        const float4* hp = (const float4*)(sh_h + kq * 40);
        float4 hv[8];
        #pragma unroll
        for (int i = 0; i < 8; ++i) hv[i] = hp[i];

        float pa[2][4];
        #pragma unroll
        for (int u = 0; u < 2; ++u) {
            #pragma unroll
            for (int g = 0; g < 4; ++g) {
                float a0 = 0.f, a1 = 0.f;
                #pragma unroll
                for (int i = 0; i < 8; ++i) {
                    float4 w = w4[u][g][i], h = hv[i];
                    a0 = fmaf(w.x, h.x, a0); a1 = fmaf(w.y, h.y, a1);
                    a0 = fmaf(w.z, h.z, a0); a1 = fmaf(w.w, h.w, a1);
                }
                pa[u][g] = a0 + a1;
            }
        }
        #pragma unroll
        for (int u = 0; u < 2; ++u) {
            float4 pv; pv.x = pa[u][0]; pv.y = pa[u][1];
            pv.z = pa[u][2]; pv.w = pa[u][3];
            *(float4*)(sh_part + (un + u * 64) * 20 + kq * 4) = pv;
        }
        __syncthreads();

        if (q < 128) {
            const float4* pp = (const float4*)(sh_part + q * 20);
            float4 r0 = pp[0], r1 = pp[1], r2 = pp[2], r3 = pp[3];
            float zi = za0 + ((r0.x + r1.x) + (r2.x + r3.x));
            float zf = za1 + ((r0.y + r1.y) + (r2.y + r3.y));
            float zg = za2 + ((r0.z + r1.z) + (r2.z + r3.z));
            float zo = za3 + ((r0.w + r1.w) + (r2.w + r3.w));
            c = sigm(zf) * c + sigm(zi) * tanhf(zg);
            float hnew = sigm(zo) * tanhf(c);
            sh_h[(q >> 5) * 40 + (q & 31)] = hnew;
            const int s_glob = dir ? (base_r + (L - 1 - t)) : (base_f + t);
            H[((size_t)s_glob * 64 + b) * 256 + dir * 128 + q] = hnew;
        }
        __syncthreads();

        za0 = zb0; za1 = zb1; za2 = zb2; za3 = zb3;
    }

    if (q < 128) {
        stp[q]       = sh_h[(q >> 5) * 40 + (q & 31)];
        stp[128 + q] = c;
    }
}

// ---------------------------------------------------------------------------
// Kernel 3: emissions  F[r][t] = H[r] . w_out[t] + b_out[t]
// ---------------------------------------------------------------------------
__global__ __launch_bounds__(256) void emissions_k(
    const float* __restrict__ H, const float* __restrict__ w_out,
    const float* __restrict__ b_out, float* __restrict__ F)
{
    const int gid = blockIdx.x * 256 + threadIdx.x;
    const int r   = gid >> 2;
    const int tg  = gid & 3;
    const float4* h4 = (const float4*)(H + (size_t)r * 256);
    const float4* w4 = (const float4*)(w_out + (size_t)tg * 256);
    float a0 = 0.f, a1 = 0.f, a2 = 0.f, a3 = 0.f;
    #pragma unroll 8
    for (int k = 0; k < 64; ++k) {
        float4 h = h4[k], w = w4[k];
        a0 = fmaf(h.x, w.x, a0); a1 = fmaf(h.y, w.y, a1);
        a2 = fmaf(h.z, w.z, a2); a3 = fmaf(h.w, w.w, a3);
    }
    F[gid] = ((a0 + a1) + (a2 + a3)) + b_out[tg];
}

// ---------------------------------------------------------------------------
// Kernel 4: Viterbi. One block (1 wave) per batch.
// ---------------------------------------------------------------------------
__device__ __forceinline__ unsigned compose_map(unsigned a, unsigned b) {
    unsigned r = 0;
    #pragma unroll
    for (int jj = 0; jj < 4; ++jj) {
        unsigned bj = (b >> (jj * 8)) & 3u;
        unsigned aj = (a >> (bj * 8)) & 3u;
        r |= aj << (jj * 8);
    }
    return r;
}

__global__ __launch_bounds__(64) void viterbi_k(
    const float* __restrict__ F, const float* __restrict__ start_t,
    const float* __restrict__ end_t, const float* __restrict__ trans,
    int* __restrict__ out)
{
    const int b    = blockIdx.x;
    const int lane = threadIdx.x;
    __shared__ __align__(16) float sfeat[SLEN][NTAG];
    __shared__ unsigned sbp[SLEN];

    #pragma unroll
    for (int i = 0; i < 16; ++i) {
        int s = i * 64 + lane;
        ((float4*)sfeat)[s] = *(const float4*)(F + ((size_t)s * BATCH + b) * NTAG);
    }
    __syncthreads();

    const int cur = lane & 3;
    float tr0 = trans[0 * 4 + cur], tr1 = trans[1 * 4 + cur];
    float tr2 = trans[2 * 4 + cur], tr3 = trans[3 * 4 + cur];
    float sc = start_t[cur] + sfeat[0][cur];

    for (int s = 1; s < SLEN; ++s) {
        float ft = sfeat[s][cur];
        float s0 = __shfl(sc, 0), s1 = __shfl(sc, 1);
        float s2 = __shfl(sc, 2), s3 = __shfl(sc, 3);
        float c0 = s0 + tr0, c1 = s1 + tr1, c2 = s2 + tr2, c3 = s3 + tr3;
        float best = c0; int arg = 0;
        if (c1 > best) { best = c1; arg = 1; }
        if (c2 > best) { best = c2; arg = 2; }
        if (c3 > best) { best = c3; arg = 3; }
        sc = best + ft;
        unsigned bp = (unsigned)arg;
        unsigned b0 = __shfl(bp, 0), b1 = __shfl(bp, 1);
        unsigned b2 = __shfl(bp, 2), b3 = __shfl(bp, 3);
        if (lane == 0) sbp[s] = b0 | (b1 << 8) | (b2 << 16) | (b3 << 24);
    }
    sc += end_t[cur];
    float f0 = __shfl(sc, 0), f1 = __shfl(sc, 1);
    float f2 = __shfl(sc, 2), f3 = __shfl(sc, 3);
    int last = 0; float bb = f0;
    if (f1 > bb) { bb = f1; last = 1; }
    if (f2 > bb) { bb = f2; last = 2; }
    if (f3 > bb) { bb = f3; last = 3; }
    __syncthreads();

    unsigned m[16];
    #pragma unroll
    for (int k = 0; k < 16; ++k) {
        int s = lane * 16 + k;
        m[k] = (s >= 1) ? sbp[s] : 0x03020100u;
    }
    unsigned G = m[15];
    #pragma unroll
    for (int k = 14; k >= 0; --k) G = compose_map(m[k], G);
    unsigned R = G;
    #pragma unroll
    for (int d = 1; d < 64; d <<= 1) {
        unsigned o = __shfl_down(R, d);
        if (lane + d < 64) R = compose_map(R, o);
    }
    unsigned P = __shfl_down(R, 1);
    if (lane == 63) P = 0x03020100u;

    int tcur = (int)((P >> (last * 8)) & 3u);
    int* ob = out + b * SLEN + lane * 16;
    ob[15] = tcur;
    #pragma unroll
    for (int k = 15; k >= 1; --k) {
        tcur = (int)((m[k] >> (tcur * 8)) & 3u);
        ob[k - 1] = tcur;
    }
}

// ---------------------------------------------------------------------------
extern "C" void kernel_launch(void* const* d_in, const int* in_sizes, int n_in,
                              void* d_out, int out_size, void* d_ws, size_t ws_size,
                              hipStream_t stream)
{
    const int*   sent    = (const int*)d_in[0];
    const float* embed   = (const float*)d_in[1];
    const float* w_ih_f  = (const float*)d_in[2];
    const float* w_hh_f  = (const float*)d_in[3];
    const float* b_ih_f  = (const float*)d_in[4];
    const float* b_hh_f  = (const float*)d_in[5];
    const float* w_ih_r  = (const float*)d_in[6];
    const float* w_hh_r  = (const float*)d_in[7];
    const float* b_ih_r  = (const float*)d_in[8];
    const float* b_hh_r  = (const float*)d_in[9];
    const float* w_out   = (const float*)d_in[10];
    const float* b_out   = (const float*)d_in[11];
    const float* start_t = (const float*)d_in[12];
    const float* end_t   = (const float*)d_in[13];
    const float* trans   = (const float*)d_in[14];
    int* out = (int*)d_out;

    const size_t H_FLOATS  = (size_t)SLEN * BATCH * 256;   // 16777216
    const size_t F_FLOATS  = (size_t)SLEN * BATCH * NTAG;  //   262144
    const size_t ST_FLOATS = (size_t)2 * BATCH * 256;      //    32768
    const size_t FIXED = H_FLOATS + F_FLOATS + ST_FLOATS;

    int L = SLEN;
    while (L > 32) {
        size_t need = ((size_t)L * BATCH * 1024 + FIXED) * sizeof(float);
        if (need <= ws_size) break;
        L >>= 1;
    }

    float* Z  = (float*)d_ws;
    float* H  = Z + (size_t)L * BATCH * 1024;
    float* F  = H + H_FLOATS;
    float* ST = F + F_FLOATS;

    const int nch = SLEN / L;
    for (int c = 0; c < nch; ++c) {
        const int base_f = c * L;
        const int base_r = SLEN - (c + 1) * L;
        gemm_zin<<<dim3(L / 2, 8), 256, 0, stream>>>(
            sent, embed, w_ih_f, w_ih_r, b_ih_f, b_hh_f, b_ih_r, b_hh_r,
            Z, base_f, base_r);
        lstm_rec<<<128, 256, 0, stream>>>(
            Z, w_hh_f, w_hh_r, H, ST, base_f, base_r, L, c == 0 ? 1 : 0);
    }
    emissions_k<<<1024, 256, 0, stream>>>(H, w_out, b_out, F);
    viterbi_k<<<64, 64, 0, stream>>>(F, start_t, end_t, trans, out);
}

// Round 6
// 1748.447 us; speedup vs baseline: 1.2135x; 1.0381x over previous
//
#include <hip/hip_runtime.h>
#include <cstdint>

#define SLEN 1024
#define BATCH 64
#define EDIM 256
#define HDIM 128   // hidden per direction
#define GDIM 512   // 4*HDIM
#define NTAG 4

typedef float f2 __attribute__((ext_vector_type(2)));

// ---------------------------------------------------------------------------
// ws layout (floats), chunked to fit ws_size:
//   Z  : [L][B][1024]  gate-preactivation chunk (cols 0..511 fwd, 512..1023 rev)
//   H  : [S][B][256]   (cols 0..127 fwd h, 128..255 rev h)      16777216
//   F  : [S][B][4]     emissions                                   262144
//   ST : [2][B][256]   LSTM carry (h | c) per (dir,b)               32768
// ---------------------------------------------------------------------------

// fast gates: v_exp_f32-based; error ~1e-7 abs, Viterbi margins ~1e-1.
__device__ __forceinline__ float sigm_f(float x) {
    return 1.0f / (1.0f + __expf(-x));
}
__device__ __forceinline__ float tanh_f(float x) {
    // 1 - 2/(e^{2x}+1): exact at 0, saturates correctly at +/-inf
    return 1.0f - 2.0f / (1.0f + __expf(2.0f * x));
}

// DPP quad-perm: ctrl must be a compile-time constant -> template parameter.
template <int CTRL>
__device__ __forceinline__ float quad_perm(float x) {
    return __int_as_float(
        __builtin_amdgcn_mov_dpp(__float_as_int(x), CTRL, 0xF, 0xF, true));
}
#define QP_XOR1 0xB1   // quad_perm [1,0,3,2]
#define QP_XOR2 0x4E   // quad_perm [2,3,0,1]

// ---------------------------------------------------------------------------
// Kernel 1: fused embedding-gather + input-projection GEMM for one S-chunk.
// 128x128 tile, kc=64, 256 threads, 8x8 micro, pk-fma via f2.
// ---------------------------------------------------------------------------
__global__ __launch_bounds__(256) void gemm_zin(
    const int* __restrict__ sent, const float* __restrict__ embed,
    const float* __restrict__ w_ih_f, const float* __restrict__ w_ih_r,
    const float* __restrict__ b_ih_f, const float* __restrict__ b_hh_f,
    const float* __restrict__ b_ih_r, const float* __restrict__ b_hh_r,
    float* __restrict__ Z, int base_f, int base_r)
{
    __shared__ __align__(16) float As[64 * 128];
    __shared__ __align__(16) float Bs[64 * 128];

    const int t   = threadIdx.x;
    const int mt  = blockIdx.x;
    const int nt  = blockIdx.y;
    const int dir = nt >> 2;
    const float* W  = dir ? w_ih_r : w_ih_f;
    const float* bi = dir ? b_ih_r : b_ih_f;
    const float* bh = dir ? b_hh_r : b_hh_f;
    const int ncol = (nt & 3) * 128;
    const int r0   = mt * 128;

    const int srow = t >> 1;
    const int half = t & 1;
    const int r_loc = r0 + srow;
    const int s_loc = r_loc >> 6;
    const int b_    = r_loc & 63;
    const int s_glob = (dir ? base_r : base_f) + s_loc;
    const int tok = sent[b_ * SLEN + s_glob];
    const float* arow = embed + (size_t)tok * EDIM + half * 32;
    const float* brow = W + (size_t)(ncol + srow) * EDIM + half * 32;

    const int tx = t & 15, ty = t >> 4;

    f2 acc[8][4];
    #pragma unroll
    for (int i = 0; i < 8; ++i)
        #pragma unroll
        for (int jj = 0; jj < 4; ++jj) { acc[i][jj] = (f2)(0.0f); }

    for (int kt = 0; kt < 4; ++kt) {
        const int k0 = kt * 64;
        __syncthreads();
        #pragma unroll
        for (int i = 0; i < 8; ++i) {
            float4 v = *(const float4*)(arow + k0 + i * 4);
            int kk = half * 32 + i * 4;
            As[(kk + 0) * 128 + srow] = v.x;
            As[(kk + 1) * 128 + srow] = v.y;
            As[(kk + 2) * 128 + srow] = v.z;
            As[(kk + 3) * 128 + srow] = v.w;
        }
        #pragma unroll
        for (int i = 0; i < 8; ++i) {
            float4 v = *(const float4*)(brow + k0 + i * 4);
            int kk = half * 32 + i * 4;
            Bs[(kk + 0) * 128 + srow] = v.x;
            Bs[(kk + 1) * 128 + srow] = v.y;
            Bs[(kk + 2) * 128 + srow] = v.z;
            Bs[(kk + 3) * 128 + srow] = v.w;
        }
        __syncthreads();

        #pragma unroll 8
        for (int k = 0; k < 64; ++k) {
            const float4 a0 = *(const float4*)&As[k * 128 + ty * 8];
            const float4 a1 = *(const float4*)&As[k * 128 + ty * 8 + 4];
            const float4 bq0 = *(const float4*)&Bs[k * 128 + tx * 8];
            const float4 bq1 = *(const float4*)&Bs[k * 128 + tx * 8 + 4];
            float av[8] = {a0.x, a0.y, a0.z, a0.w, a1.x, a1.y, a1.z, a1.w};
            f2 bv[4];
            bv[0].x = bq0.x; bv[0].y = bq0.y;
            bv[1].x = bq0.z; bv[1].y = bq0.w;
            bv[2].x = bq1.x; bv[2].y = bq1.y;
            bv[3].x = bq1.z; bv[3].y = bq1.w;
            #pragma unroll
            for (int i = 0; i < 8; ++i) {
                f2 as; as.x = av[i]; as.y = av[i];
                #pragma unroll
                for (int jj = 0; jj < 4; ++jj) {
                    acc[i][jj] += as * bv[jj];   // v_pk_fma_f32
                }
            }
        }
    }

    float bias[8];
    #pragma unroll
    for (int jj = 0; jj < 8; ++jj)
        bias[jj] = bi[ncol + tx * 8 + jj] + bh[ncol + tx * 8 + jj];

    #pragma unroll
    for (int i = 0; i < 8; ++i) {
        int rr = r0 + ty * 8 + i;
        float* zp = Z + (size_t)rr * 1024 + dir * 512 + ncol + tx * 8;
        float4 o0, o1;
        o0.x = acc[i][0].x + bias[0]; o0.y = acc[i][0].y + bias[1];
        o0.z = acc[i][1].x + bias[2]; o0.w = acc[i][1].y + bias[3];
        o1.x = acc[i][2].x + bias[4]; o1.y = acc[i][2].y + bias[5];
        o1.z = acc[i][3].x + bias[6]; o1.w = acc[i][3].y + bias[7];
        *(float4*)zp       = o0;
        *(float4*)(zp + 4) = o1;
    }
}

// ---------------------------------------------------------------------------
// Kernel 2 (v3): LSTM recurrence, 1 barrier/step, amortized drains.
// 128 blocks (batch x dir), 256 threads (4 waves).
// Quad Q = q>>2 owns units uA=Q, uB=Q+64; lane p=q&3 owns k in [32p,32p+32).
// Per step: broadcast h from ping-pong LDS buffer, 128 v_pk_fma (8 dots of
// 32k), DPP quad butterfly reduce, fast gates (replicated in quad), p==0
// writes h to other buffer, ONE __syncthreads. Z loaded 4 steps/batch,
// double-buffered in regs; H stores buffered 4 steps. w_hh register-resident.
// ---------------------------------------------------------------------------
__global__ __launch_bounds__(256, 1) void lstm_rec(
    const float* __restrict__ Z, const float* __restrict__ w_hh_f,
    const float* __restrict__ w_hh_r, float* __restrict__ H,
    float* __restrict__ ST, int base_f, int base_r, int L, int first)
{
    const int bid = blockIdx.x;
    const int b   = bid & 63;
    const int dir = bid >> 6;
    const int q   = threadIdx.x;
    const int p   = q & 3;    // k-slice
    const int Q   = q >> 2;   // quad id
    const int uA  = Q;
    const int uB  = Q + 64;

    const float* Whh = dir ? w_hh_r : w_hh_f;

    // register-resident weights: [u2][gate][16 f2] over k in [32p,32p+32)
    f2 w2[2][4][16];
    #pragma unroll
    for (int u2 = 0; u2 < 2; ++u2) {
        const int u = u2 ? uB : uA;
        #pragma unroll
        for (int g = 0; g < 4; ++g) {
            const float4* src =
                (const float4*)(Whh + ((size_t)(g * 128 + u) * 128 + p * 32));
            #pragma unroll
            for (int i = 0; i < 8; ++i) {
                float4 v = src[i];
                w2[u2][g][2 * i].x     = v.x; w2[u2][g][2 * i].y     = v.y;
                w2[u2][g][2 * i + 1].x = v.z; w2[u2][g][2 * i + 1].y = v.w;
            }
        }
    }

    // ping-pong h: h[k] at (k>>5)*36 + (k&31); p-groups hit disjoint banks
    __shared__ __align__(16) float sh_h[2][160];

    float* stp = ST + (size_t)(dir * 64 + b) * 256;
    if (q < 128)
        sh_h[0][(q >> 5) * 36 + (q & 31)] = first ? 0.0f : stp[q];
    float cA = first ? 0.0f : stp[128 + uA];
    float cB = first ? 0.0f : stp[128 + uB];

    // Z batched loads: 4 steps per batch, double-buffered in regs
    const float* Zbase = Z + (size_t)b * 1024 + dir * 512;
    float zcur[4][2][4], znxt[4][2][4];
    #pragma unroll
    for (int dt = 0; dt < 4; ++dt) {
        const int s_loc = dir ? (L - 1 - dt) : dt;
        const float* zp = Zbase + (size_t)s_loc * 65536;
        #pragma unroll
        for (int u2 = 0; u2 < 2; ++u2)
            #pragma unroll
            for (int g = 0; g < 4; ++g)
                zcur[dt][u2][g] = zp[g * 128 + (u2 ? uB : uA)];
    }
    __syncthreads();

    float hAo[4], hBo[4];

    for (int t0 = 0; t0 < L; t0 += 4) {
        const bool more = (t0 + 4 < L);
        if (more) {
            #pragma unroll
            for (int dt = 0; dt < 4; ++dt) {
                const int tt = t0 + 4 + dt;
                const int s_loc = dir ? (L - 1 - tt) : tt;
                const float* zp = Zbase + (size_t)s_loc * 65536;
                #pragma unroll
                for (int u2 = 0; u2 < 2; ++u2)
                    #pragma unroll
                    for (int g = 0; g < 4; ++g)
                        znxt[dt][u2][g] = zp[g * 128 + (u2 ? uB : uA)];
            }
        }

        #pragma unroll
        for (int dt = 0; dt < 4; ++dt) {
            const int t = t0 + dt;
            // broadcast h slice [32p, 32p+32)
            const float4* hp = (const float4*)(&sh_h[t & 1][0] + p * 36);
            f2 hv[16];
            #pragma unroll
            for (int i = 0; i < 8; ++i) {
                float4 v = hp[i];
                hv[2 * i].x     = v.x; hv[2 * i].y     = v.y;
                hv[2 * i + 1].x = v.z; hv[2 * i + 1].y = v.w;
            }
            // 8 partial dots over 32 k
            float z8[2][4];
            #pragma unroll
            for (int u2 = 0; u2 < 2; ++u2) {
                #pragma unroll
                for (int g = 0; g < 4; ++g) {
                    f2 a = (f2)(0.0f);
                    #pragma unroll
                    for (int i = 0; i < 16; ++i)
                        a += w2[u2][g][i] * hv[i];   // v_pk_fma_f32
                    z8[u2][g] = a.x + a.y;
                }
            }
            // quad butterfly + add Z input
            #pragma unroll
            for (int u2 = 0; u2 < 2; ++u2)
                #pragma unroll
                for (int g = 0; g < 4; ++g) {
                    float v = z8[u2][g];
                    v += quad_perm<QP_XOR1>(v);
                    v += quad_perm<QP_XOR2>(v);
                    z8[u2][g] = v + zcur[dt][u2][g];
                }
            // gates (replicated across quad)
            float iA = sigm_f(z8[0][0]), fA = sigm_f(z8[0][1]);
            float gA = tanh_f(z8[0][2]), oA = sigm_f(z8[0][3]);
            cA = fA * cA + iA * gA;
            float hA = oA * tanh_f(cA);
            float iB = sigm_f(z8[1][0]), fB = sigm_f(z8[1][1]);
            float gB = tanh_f(z8[1][2]), oB = sigm_f(z8[1][3]);
            cB = fB * cB + iB * gB;
            float hB = oB * tanh_f(cB);
            hAo[dt] = hA; hBo[dt] = hB;

            if (p == 0) {
                float* hn = &sh_h[(t + 1) & 1][0];
                hn[(uA >> 5) * 36 + (uA & 31)] = hA;
                hn[(uB >> 5) * 36 + (uB & 31)] = hB;
            }
            __syncthreads();
        }

        // buffered H stores (drain amortized over 4 steps)
        if (p == 0) {
            #pragma unroll
            for (int dt = 0; dt < 4; ++dt) {
                const int t = t0 + dt;
                const int s_glob = dir ? (base_r + (L - 1 - t)) : (base_f + t);
                float* hg = H + ((size_t)s_glob * 64 + b) * 256 + dir * 128;
                hg[uA] = hAo[dt];
                hg[uB] = hBo[dt];
            }
        }
        if (more) {
            #pragma unroll
            for (int dt = 0; dt < 4; ++dt)
                #pragma unroll
                for (int u2 = 0; u2 < 2; ++u2)
                    #pragma unroll
                    for (int g = 0; g < 4; ++g)
                        zcur[dt][u2][g] = znxt[dt][u2][g];
        }
    }

    if (p == 0) {
        stp[uA] = hAo[3];  stp[uB] = hBo[3];
        stp[128 + uA] = cA; stp[128 + uB] = cB;
    }
}

// ---------------------------------------------------------------------------
// Kernel 3: emissions  F[r][t] = H[r] . w_out[t] + b_out[t]
// ---------------------------------------------------------------------------
__global__ __launch_bounds__(256) void emissions_k(
    const float* __restrict__ H, const float* __restrict__ w_out,
    const float* __restrict__ b_out, float* __restrict__ F)
{
    const int gid = blockIdx.x * 256 + threadIdx.x;
    const int r   = gid >> 2;
    const int tg  = gid & 3;
    const float4* h4 = (const float4*)(H + (size_t)r * 256);
    const float4* w4 = (const float4*)(w_out + (size_t)tg * 256);
    float a0 = 0.f, a1 = 0.f, a2 = 0.f, a3 = 0.f;
    #pragma unroll 8
    for (int k = 0; k < 64; ++k) {
        float4 h = h4[k], w = w4[k];
        a0 = fmaf(h.x, w.x, a0); a1 = fmaf(h.y, w.y, a1);
        a2 = fmaf(h.z, w.z, a2); a3 = fmaf(h.w, w.w, a3);
    }
    F[gid] = ((a0 + a1) + (a2 + a3)) + b_out[tg];
}

// ---------------------------------------------------------------------------
// Kernel 4: Viterbi. One block (1 wave) per batch.
// ---------------------------------------------------------------------------
__device__ __forceinline__ unsigned compose_map(unsigned a, unsigned b) {
    unsigned r = 0;
    #pragma unroll
    for (int jj = 0; jj < 4; ++jj) {
        unsigned bj = (b >> (jj * 8)) & 3u;
        unsigned aj = (a >> (bj * 8)) & 3u;
        r |= aj << (jj * 8);
    }
    return r;
}

__global__ __launch_bounds__(64) void viterbi_k(
    const float* __restrict__ F, const float* __restrict__ start_t,
    const float* __restrict__ end_t, const float* __restrict__ trans,
    int* __restrict__ out)
{
    const int b    = blockIdx.x;
    const int lane = threadIdx.x;
    __shared__ __align__(16) float sfeat[SLEN][NTAG];
    __shared__ unsigned sbp[SLEN];

    #pragma unroll
    for (int i = 0; i < 16; ++i) {
        int s = i * 64 + lane;
        ((float4*)sfeat)[s] = *(const float4*)(F + ((size_t)s * BATCH + b) * NTAG);
    }
    __syncthreads();

    const int cur = lane & 3;
    float tr0 = trans[0 * 4 + cur], tr1 = trans[1 * 4 + cur];
    float tr2 = trans[2 * 4 + cur], tr3 = trans[3 * 4 + cur];
    float sc = start_t[cur] + sfeat[0][cur];

    for (int s = 1; s < SLEN; ++s) {
        float ft = sfeat[s][cur];
        float s0 = __shfl(sc, 0), s1 = __shfl(sc, 1);
        float s2 = __shfl(sc, 2), s3 = __shfl(sc, 3);
        float c0 = s0 + tr0, c1 = s1 + tr1, c2 = s2 + tr2, c3 = s3 + tr3;
        float best = c0; int arg = 0;
        if (c1 > best) { best = c1; arg = 1; }
        if (c2 > best) { best = c2; arg = 2; }
        if (c3 > best) { best = c3; arg = 3; }
        sc = best + ft;
        unsigned bp = (unsigned)arg;
        unsigned b0 = __shfl(bp, 0), b1 = __shfl(bp, 1);
        unsigned b2 = __shfl(bp, 2), b3 = __shfl(bp, 3);
        if (lane == 0) sbp[s] = b0 | (b1 << 8) | (b2 << 16) | (b3 << 24);
    }
    sc += end_t[cur];
    float f0 = __shfl(sc, 0), f1 = __shfl(sc, 1);
    float f2v = __shfl(sc, 2), f3 = __shfl(sc, 3);
    int last = 0; float bb = f0;
    if (f1 > bb)  { bb = f1;  last = 1; }
    if (f2v > bb) { bb = f2v; last = 2; }
    if (f3 > bb)  { bb = f3;  last = 3; }
    __syncthreads();

    unsigned m[16];
    #pragma unroll
    for (int k = 0; k < 16; ++k) {
        int s = lane * 16 + k;
        m[k] = (s >= 1) ? sbp[s] : 0x03020100u;
    }
    unsigned G = m[15];
    #pragma unroll
    for (int k = 14; k >= 0; --k) G = compose_map(m[k], G);
    unsigned R = G;
    #pragma unroll
    for (int d = 1; d < 64; d <<= 1) {
        unsigned o = __shfl_down(R, d);
        if (lane + d < 64) R = compose_map(R, o);
    }
    unsigned P = __shfl_down(R, 1);
    if (lane == 63) P = 0x03020100u;

    int tcur = (int)((P >> (last * 8)) & 3u);
    int* ob = out + b * SLEN + lane * 16;
    ob[15] = tcur;
    #pragma unroll
    for (int k = 15; k >= 1; --k) {
        tcur = (int)((m[k] >> (tcur * 8)) & 3u);
        ob[k - 1] = tcur;
    }
}

// ---------------------------------------------------------------------------
extern "C" void kernel_launch(void* const* d_in, const int* in_sizes, int n_in,
                              void* d_out, int out_size, void* d_ws, size_t ws_size,
                              hipStream_t stream)
{
    const int*   sent    = (const int*)d_in[0];
    const float* embed   = (const float*)d_in[1];
    const float* w_ih_f  = (const float*)d_in[2];
    const float* w_hh_f  = (const float*)d_in[3];
    const float* b_ih_f  = (const float*)d_in[4];
    const float* b_hh_f  = (const float*)d_in[5];
    const float* w_ih_r  = (const float*)d_in[6];
    const float* w_hh_r  = (const float*)d_in[7];
    const float* b_ih_r  = (const float*)d_in[8];
    const float* b_hh_r  = (const float*)d_in[9];
    const float* w_out   = (const float*)d_in[10];
    const float* b_out   = (const float*)d_in[11];
    const float* start_t = (const float*)d_in[12];
    const float* end_t   = (const float*)d_in[13];
    const float* trans   = (const float*)d_in[14];
    int* out = (int*)d_out;

    const size_t H_FLOATS  = (size_t)SLEN * BATCH * 256;   // 16777216
    const size_t F_FLOATS  = (size_t)SLEN * BATCH * NTAG;  //   262144
    const size_t ST_FLOATS = (size_t)2 * BATCH * 256;      //    32768
    const size_t FIXED = H_FLOATS + F_FLOATS + ST_FLOATS;

    int L = SLEN;
    while (L > 32) {
        size_t need = ((size_t)L * BATCH * 1024 + FIXED) * sizeof(float);
        if (need <= ws_size) break;
        L >>= 1;
    }

    float* Z  = (float*)d_ws;
    float* H  = Z + (size_t)L * BATCH * 1024;
    float* F  = H + H_FLOATS;
    float* ST = F + F_FLOATS;

    const int nch = SLEN / L;
    for (int c = 0; c < nch; ++c) {
        const int base_f = c * L;
        const int base_r = SLEN - (c + 1) * L;
        gemm_zin<<<dim3(L / 2, 8), 256, 0, stream>>>(
            sent, embed, w_ih_f, w_ih_r, b_ih_f, b_hh_f, b_ih_r, b_hh_r,
            Z, base_f, base_r);
        lstm_rec<<<128, 256, 0, stream>>>(
            Z, w_hh_f, w_hh_r, H, ST, base_f, base_r, L, c == 0 ? 1 : 0);
    }
    emissions_k<<<1024, 256, 0, stream>>>(H, w_out, b_out, F);
    viterbi_k<<<64, 64, 0, stream>>>(F, start_t, end_t, trans, out);
}